// Round 6
// baseline (709.071 us; speedup 1.0000x reference)
//
#include <hip/hip_runtime.h>
#include <hip/hip_bf16.h>

#define BB 16384
#define KK 3
#define DD 1024
#define HH 16

typedef __attribute__((ext_vector_type(8))) short bf16x8;
typedef __attribute__((ext_vector_type(4))) float f32x4;
typedef unsigned int u32;

__device__ __forceinline__ void load_lds16(const void* g, void* l) {
  __builtin_amdgcn_global_load_lds(
      (const __attribute__((address_space(1))) u32*)g,
      (__attribute__((address_space(3))) u32*)l,
      16, 0, 0);
}

__device__ __forceinline__ unsigned short f2bf(float f) {
  __hip_bfloat16 h = __float2bfloat16(f);
  unsigned short u;
  __builtin_memcpy(&u, &h, 2);
  return u;
}

__device__ __forceinline__ float bf2f(unsigned short u) {
  union { float f; u32 i; } cv;
  cv.i = ((u32)u) << 16;
  return cv.f;
}

// ---------------------------------------------------------------- cast fp32 -> bf16
__global__ void cast_f32_bf16(const float* __restrict__ in,
                              unsigned short* __restrict__ out, int n4) {
  int stride = gridDim.x * blockDim.x;
  for (int i = blockIdx.x * blockDim.x + threadIdx.x; i < n4; i += stride) {
    float4 v = ((const float4*)in)[i];
    ushort4 o;
    o.x = f2bf(v.x);
    o.y = f2bf(v.y);
    o.z = f2bf(v.z);
    o.w = f2bf(v.w);
    ((ushort4*)out)[i] = o;
  }
}

// ================================================================ CONTROL
// Best-known (R4 bench: QKV 363us, MfmaUtil 38). 256x256, 8 waves (2Mx4N),
// wave-tile 128x64, 4-slot ring, 2 fine phases/K32-tile, vmcnt(8) steady.
template <bool OUT_F32>
__global__ __launch_bounds__(512, 2)
void gemm256(const __hip_bfloat16* __restrict__ A,
             const __hip_bfloat16* __restrict__ Bt,
             const float* __restrict__ bias,
             void* __restrict__ Cout,
             int M, int N, int K) {
  __shared__ __align__(128) char lds[131072];

  const int nTn = N >> 8;
  const int nwg = (M >> 8) * nTn;
  int bid = blockIdx.x;
  bid = (bid & 7) * (nwg >> 3) + (bid >> 3);  // bijective XCD swizzle (nwg%8==0)
  const int tm = bid / nTn;
  const int tn = bid % nTn;

  const int tid = threadIdx.x;
  const int l = tid & 63;
  const int w = tid >> 6;
  const int wm = w >> 2;   // 0..1
  const int wn = w & 3;    // 0..3
  const int l15 = l & 15;
  const int g = l >> 4;    // k-chunk group 0..3
  const int l7 = l15 & 7;

  const int aBase = (l15 << 7) + (((wm << 2) + g) ^ l7) * 16;
  const int bBase = 16384 + ((((wn & 1) << 6) + l15) << 7) +
                    ((((wn >> 1) << 2) + g) ^ l7) * 16;

  const size_t strideK = (size_t)K * 2;
  const char* Ab = (const char*)A + (size_t)tm * 256 * strideK;
  const char* Bb = (const char*)Bt + (size_t)tn * 256 * strideK;
  const int q = (tid & 7) ^ ((tid >> 3) & 7);
  const size_t g0 = (size_t)((q >> 2) * 128 + (tid >> 3)) * strideK + (q & 3) * 16;
  const size_t g1 = g0 + (size_t)64 * strideK;
  const int sld = tid << 4;

  f32x4 acc[8][4] = {};
  const int nkt = K >> 5;  // BK = 32

#define STAGE_A(T)                                                        \
  {                                                                       \
    char* sb = lds + (((T) & 3) << 15);                                   \
    const char* ga = Ab + ((size_t)(T) << 6);                             \
    load_lds16(ga + g0, sb + sld);                                        \
    load_lds16(ga + g1, sb + 8192 + sld);                                 \
  }
#define STAGE_B(T)                                                        \
  {                                                                       \
    char* sb = lds + (((T) & 3) << 15);                                   \
    const char* gb = Bb + ((size_t)(T) << 6);                             \
    load_lds16(gb + g0, sb + 16384 + sld);                                \
    load_lds16(gb + g1, sb + 24576 + sld);                                \
  }
#define MFMA_HALF(H)                                                      \
  __builtin_amdgcn_s_setprio(1);                                          \
  _Pragma("unroll") for (int mm = 0; mm < 4; ++mm)                        \
      _Pragma("unroll") for (int nn = 0; nn < 4; ++nn)                    \
          acc[(H) + mm][nn] = __builtin_amdgcn_mfma_f32_16x16x32_bf16(    \
              af[mm], bfr[nn], acc[(H) + mm][nn], 0, 0, 0);               \
  __builtin_amdgcn_s_setprio(0);

  STAGE_A(0); STAGE_B(0);
  STAGE_A(1); STAGE_B(1);
  STAGE_A(2); STAGE_B(2);
  asm volatile("s_waitcnt vmcnt(8)" ::: "memory");
  __builtin_amdgcn_s_barrier();

  for (int kt = 0; kt < nkt; ++kt) {
    const char* slot = lds + ((kt & 3) << 15);
    bf16x8 af[4], bfr[4];

#pragma unroll
    for (int n = 0; n < 4; ++n)
      bfr[n] = *(const bf16x8*)(slot + bBase + (n << 11));
#pragma unroll
    for (int m = 0; m < 4; ++m)
      af[m] = *(const bf16x8*)(slot + aBase + (m << 11));
    if (kt + 3 < nkt) STAGE_A(kt + 3);
    __builtin_amdgcn_s_barrier();
    asm volatile("s_waitcnt lgkmcnt(0)" ::: "memory");
    MFMA_HALF(0)
    __builtin_amdgcn_s_barrier();

#pragma unroll
    for (int m = 0; m < 4; ++m)
      af[m] = *(const bf16x8*)(slot + aBase + ((m + 4) << 11));
    if (kt + 3 < nkt) STAGE_B(kt + 3);
    if (kt < nkt - 3)
      asm volatile("s_waitcnt vmcnt(8)" ::: "memory");
    else if (kt == nkt - 3)
      asm volatile("s_waitcnt vmcnt(4)" ::: "memory");
    else if (kt == nkt - 2)
      asm volatile("s_waitcnt vmcnt(0)" ::: "memory");
    __builtin_amdgcn_s_barrier();
    asm volatile("s_waitcnt lgkmcnt(0)" ::: "memory");
    MFMA_HALF(4)
    __builtin_amdgcn_s_barrier();
  }
#undef STAGE_A
#undef STAGE_B
#undef MFMA_HALF

  const int cbase = tn * 256 + (wn << 6) + l15;
  float b4[4];
#pragma unroll
  for (int n = 0; n < 4; ++n) b4[n] = bias[cbase + (n << 4)];
  const size_t rbase = (size_t)tm * 256 + (wm << 7) + ((l >> 4) << 2);
#pragma unroll
  for (int m = 0; m < 8; ++m) {
#pragma unroll
    for (int j = 0; j < 4; ++j) {
      const size_t row = rbase + (m << 4) + j;
#pragma unroll
      for (int n = 0; n < 4; ++n) {
        const int col = cbase + (n << 4);
        float v = acc[m][n][j] + b4[n];
        if (OUT_F32)
          ((float*)Cout)[row * N + col] = v;
        else
          ((unsigned short*)Cout)[row * N + col] = f2bf(v);
      }
    }
  }
}

// ================================================================ CHALLENGER
// 256x256 tile, 1024 threads = 16 waves (4Mx4N), wave-tile 64x64 (acc 64 VGPR,
// <=128 total -> 4 waves/SIMD). 3-slot LDS ring (3x32KB=96KB, 1 block/CU),
// stage kt+2, vmcnt(4) steady. Same [128 line][128B] chunk-XOR layout as
// control (verified conflict-free). Hypothesis: 4 waves/SIMD desync hides the
// read/barrier/lgkm serial windows that pin control at ~37% MfmaUtil.
template <bool OUT_F32>
__global__ __launch_bounds__(1024, 4)
void gemm_w16(const __hip_bfloat16* __restrict__ A,
              const __hip_bfloat16* __restrict__ Bt,
              const float* __restrict__ bias,
              void* __restrict__ Cout,
              int M, int N, int K) {
  __shared__ __align__(128) char lds[98304];

  const int nTn = N >> 8;
  const int nwg = (M >> 8) * nTn;
  int bid = blockIdx.x;
  bid = (bid & 7) * (nwg >> 3) + (bid >> 3);  // bijective XCD swizzle (nwg%8==0)
  const int tm = bid / nTn;
  const int tn = bid % nTn;

  const int tid = threadIdx.x;
  const int l = tid & 63;
  const int w = tid >> 6;        // 0..15
  const int wm = w >> 2;         // 0..3
  const int wn = w & 3;          // 0..3
  const int l15 = l & 15;
  const int g = l >> 4;
  const int l7 = l15 & 7;

  // fragment read offsets (within a 32KB slot); row fold: line=row&127,
  // logical chunk q=(row>>7)*4+g, phys=q^(line&7); line&7==l7 here.
  int aOff[4], bOff[4];
#pragma unroll
  for (int m = 0; m < 4; ++m) {
    const int row = (wm << 6) + (m << 4) + l15;
    aOff[m] = ((row & 127) << 7) + (((((row >> 7) << 2) + g) ^ l7) << 4);
    const int col = (wn << 6) + (m << 4) + l15;
    bOff[m] = 16384 + ((col & 127) << 7) + (((((col >> 7) << 2) + g) ^ l7) << 4);
  }

  // staging: 1024 threads x (1 A-slice + 1 B-slice) of 16B; dest linear,
  // source pre-swizzled (same involution as reads).
  const size_t strideK = (size_t)K * 2;
  const char* Ab = (const char*)A + (size_t)tm * 256 * strideK;
  const char* Bb = (const char*)Bt + (size_t)tn * 256 * strideK;
  const int line = tid >> 3;                    // 0..127
  const int q = (tid & 7) ^ (line & 7);
  const size_t gsrc = (size_t)((q >> 2) * 128 + line) * strideK +
                      (size_t)((q & 3) << 4);
  const int sld = tid << 4;

  f32x4 acc[4][4] = {};
  const int nkt = K >> 5;

#define STG16(T, S)                                                     \
  {                                                                     \
    char* sb = lds + ((S) << 15);                                       \
    load_lds16(Ab + ((size_t)(T) << 6) + gsrc, sb + sld);               \
    load_lds16(Bb + ((size_t)(T) << 6) + gsrc, sb + 16384 + sld);       \
  }

  STG16(0, 0);
  STG16(1, 1);
  int scur = 0, sstg = 2;
  for (int kt = 0; kt < nkt; ++kt) {
    if (kt + 2 < nkt) STG16(kt + 2, sstg);
    if (kt < nkt - 2)
      asm volatile("s_waitcnt vmcnt(4)" ::: "memory");
    else if (kt == nkt - 2)
      asm volatile("s_waitcnt vmcnt(2)" ::: "memory");
    else
      asm volatile("s_waitcnt vmcnt(0)" ::: "memory");
    __builtin_amdgcn_s_barrier();
    asm volatile("" ::: "memory");

    const char* slot = lds + (scur << 15);
    bf16x8 af[4], bfr[4];
#pragma unroll
    for (int m = 0; m < 4; ++m) af[m] = *(const bf16x8*)(slot + aOff[m]);
#pragma unroll
    for (int n = 0; n < 4; ++n) bfr[n] = *(const bf16x8*)(slot + bOff[n]);
    asm volatile("s_waitcnt lgkmcnt(0)" ::: "memory");
    __builtin_amdgcn_sched_barrier(0);
    __builtin_amdgcn_s_setprio(1);
#pragma unroll
    for (int m = 0; m < 4; ++m)
#pragma unroll
      for (int n = 0; n < 4; ++n)
        acc[m][n] = __builtin_amdgcn_mfma_f32_16x16x32_bf16(af[m], bfr[n],
                                                            acc[m][n], 0, 0, 0);
    __builtin_amdgcn_s_setprio(0);
    __builtin_amdgcn_s_barrier();
    asm volatile("" ::: "memory");
    scur = scur == 2 ? 0 : scur + 1;
    sstg = sstg == 2 ? 0 : sstg + 1;
  }
#undef STG16

  const int cbase = tn * 256 + (wn << 6) + l15;
  float b4[4];
#pragma unroll
  for (int n = 0; n < 4; ++n) b4[n] = bias[cbase + (n << 4)];
  const size_t rbase = (size_t)tm * 256 + (wm << 6) + ((l >> 4) << 2);
#pragma unroll
  for (int m = 0; m < 4; ++m) {
#pragma unroll
    for (int j = 0; j < 4; ++j) {
      const size_t row = rbase + (m << 4) + j;
#pragma unroll
      for (int n = 0; n < 4; ++n) {
        const int col = cbase + (n << 4);
        float v = acc[m][n][j] + b4[n];
        if (OUT_F32)
          ((float*)Cout)[row * N + col] = v;
        else
          ((unsigned short*)Cout)[row * N + col] = f2bf(v);
      }
    }
  }
}

// ---------------------------------------------------------------- attention
__global__ __launch_bounds__(256)
void attn_kernel(const unsigned short* __restrict__ QKV,  // (B*3) x 3072
                 const unsigned short* __restrict__ Cp,   // B x 1024
                 unsigned short* __restrict__ Out) {      // (B*3) x 1024
  const int t = threadIdx.x;
  const int grp = (blockIdx.x << 4) + (t >> 4);
  const int x = t & 15;
  const int b = grp >> 4;   // H = 16
  const int h = grp & 15;

  const size_t col = (size_t)h * 64 + (x << 2);
  const size_t qbase = (size_t)b * 3 * 3072 + col;

  ushort4 cu = *(const ushort4*)&Cp[(size_t)b * 1024 + col];
  float c[4] = {bf2f(cu.x), bf2f(cu.y), bf2f(cu.z), bf2f(cu.w)};

  float q[3][4], kc[3][4], vc[3][4];
#pragma unroll
  for (int i = 0; i < 3; ++i) {
    ushort4 qu = *(const ushort4*)&QKV[qbase + (size_t)i * 3072];
    ushort4 ku = *(const ushort4*)&QKV[qbase + (size_t)i * 3072 + 1024];
    ushort4 vu = *(const ushort4*)&QKV[qbase + (size_t)i * 3072 + 2048];
    q[i][0] = bf2f(qu.x); q[i][1] = bf2f(qu.y); q[i][2] = bf2f(qu.z); q[i][3] = bf2f(qu.w);
    kc[i][0] = bf2f(ku.x) * c[0]; kc[i][1] = bf2f(ku.y) * c[1];
    kc[i][2] = bf2f(ku.z) * c[2]; kc[i][3] = bf2f(ku.w) * c[3];
    vc[i][0] = bf2f(vu.x) * c[0]; vc[i][1] = bf2f(vu.y) * c[1];
    vc[i][2] = bf2f(vu.z) * c[2]; vc[i][3] = bf2f(vu.w) * c[3];
  }

  float s[9];
#pragma unroll
  for (int i = 0; i < 3; ++i)
#pragma unroll
    for (int j = 0; j < 3; ++j)
      s[i * 3 + j] = q[i][0] * kc[j][0] + q[i][1] * kc[j][1] +
                     q[i][2] * kc[j][2] + q[i][3] * kc[j][3];

#pragma unroll
  for (int off = 8; off > 0; off >>= 1)
#pragma unroll
    for (int e = 0; e < 9; ++e)
      s[e] += __shfl_xor(s[e], off, 64);

  const float scale = 0.125f;  // 1/sqrt(64)
#pragma unroll
  for (int i = 0; i < 3; ++i) {
    float s0 = s[i * 3 + 0] * scale;
    float s1 = s[i * 3 + 1] * scale;
    float s2 = s[i * 3 + 2] * scale;
    float m = fmaxf(fmaxf(s0, s1), s2);
    float p0 = expf(s0 - m), p1 = expf(s1 - m), p2 = expf(s2 - m);
    float inv = 1.0f / (p0 + p1 + p2);
    ushort4 o;
    o.x = f2bf((p0 * vc[0][0] + p1 * vc[1][0] + p2 * vc[2][0]) * inv);
    o.y = f2bf((p0 * vc[0][1] + p1 * vc[1][1] + p2 * vc[2][1]) * inv);
    o.z = f2bf((p0 * vc[0][2] + p1 * vc[1][2] + p2 * vc[2][2]) * inv);
    o.w = f2bf((p0 * vc[0][3] + p1 * vc[1][3] + p2 * vc[2][3]) * inv);
    *(ushort4*)&Out[(size_t)(b * 3 + i) * 1024 + col] = o;
  }
}

// ---------------------------------------------------------------- launch
extern "C" void kernel_launch(void* const* d_in, const int* in_sizes, int n_in,
                              void* d_out, int out_size, void* d_ws, size_t ws_size,
                              hipStream_t stream) {
  const float* tokens = (const float*)d_in[0];
  const float* ctx    = (const float*)d_in[1];
  const float* Wq     = (const float*)d_in[2];
  const float* bq     = (const float*)d_in[3];
  const float* Wk     = (const float*)d_in[4];
  const float* bk     = (const float*)d_in[5];
  const float* Wv     = (const float*)d_in[6];
  const float* bv     = (const float*)d_in[7];
  const float* Wc     = (const float*)d_in[8];
  const float* bc     = (const float*)d_in[9];
  const float* Wo     = (const float*)d_in[10];
  const float* bo     = (const float*)d_in[11];

  const int M  = BB * KK;   // 49152 token rows
  const int Mc = BB;        // 16384 ctx rows
  const int D  = DD;        // 1024
  const int Mh = M / 2;     // 24576 rows per A/B half

  char* p = (char*)d_ws;
  auto carve = [&](size_t bytes) {
    char* r = p;
    p += (bytes + 255) & ~(size_t)255;
    return r;
  };
  unsigned short* Xb   = (unsigned short*)carve((size_t)M * D * 2);  // tokens bf16; reused as attn out
  unsigned short* Cin  = (unsigned short*)carve((size_t)Mc * D * 2);
  unsigned short* Wqkv = (unsigned short*)carve((size_t)3 * D * D * 2);
  unsigned short* Wcb  = (unsigned short*)carve((size_t)D * D * 2);
  unsigned short* Wob  = (unsigned short*)carve((size_t)D * D * 2);
  float*          bqkv = (float*)carve((size_t)3 * D * 4);
  unsigned short* QKV  = (unsigned short*)carve((size_t)M * 3 * D * 2);
  unsigned short* Cpr  = (unsigned short*)carve((size_t)Mc * D * 2);

  hipLaunchKernelGGL(cast_f32_bf16, dim3(4096), dim3(256), 0, stream, tokens, Xb, M * D / 4);
  hipLaunchKernelGGL(cast_f32_bf16, dim3(2048), dim3(256), 0, stream, ctx, Cin, Mc * D / 4);
  hipLaunchKernelGGL(cast_f32_bf16, dim3(512), dim3(256), 0, stream, Wq, Wqkv, D * D / 4);
  hipLaunchKernelGGL(cast_f32_bf16, dim3(512), dim3(256), 0, stream, Wk, Wqkv + D * D, D * D / 4);
  hipLaunchKernelGGL(cast_f32_bf16, dim3(512), dim3(256), 0, stream, Wv, Wqkv + 2 * D * D, D * D / 4);
  hipLaunchKernelGGL(cast_f32_bf16, dim3(512), dim3(256), 0, stream, Wc, Wcb, D * D / 4);
  hipLaunchKernelGGL(cast_f32_bf16, dim3(512), dim3(256), 0, stream, Wo, Wob, D * D / 4);
  hipMemcpyAsync(bqkv, bq, D * 4, hipMemcpyDeviceToDevice, stream);
  hipMemcpyAsync(bqkv + D, bk, D * 4, hipMemcpyDeviceToDevice, stream);
  hipMemcpyAsync(bqkv + 2 * D, bv, D * 4, hipMemcpyDeviceToDevice, stream);

  // QKV projection, A/B split by tm half (disjoint output rows, same numerics):
  //  - CONTROL  (gemm256, 8 waves):  rows 0..24575    -> 96*12 = 1152 blocks
  //  - CHALLENGER (gemm_w16, 16 waves): rows 24576..  -> 96*12 = 1152 blocks
  hipLaunchKernelGGL((gemm256<false>), dim3((Mh / 256) * (3 * D / 256)), dim3(512), 0, stream,
                     (const __hip_bfloat16*)Xb, (const __hip_bfloat16*)Wqkv, bqkv,
                     (void*)QKV, Mh, 3 * D, D);
  hipLaunchKernelGGL((gemm_w16<false>), dim3((Mh / 256) * (3 * D / 256)), dim3(1024), 0, stream,
                     (const __hip_bfloat16*)(Xb + (size_t)Mh * D),
                     (const __hip_bfloat16*)Wqkv, bqkv,
                     (void*)(QKV + (size_t)Mh * 3 * D), Mh, 3 * D, D);

  // ctx projection (control kernel)
  hipLaunchKernelGGL((gemm256<false>), dim3((Mc / 256) * (D / 256)), dim3(512), 0, stream,
                     (const __hip_bfloat16*)Cin, (const __hip_bfloat16*)Wcb, bc,
                     (void*)Cpr, Mc, D, D);
  // attention (writes into Xb, dead after the QKV GEMM)
  hipLaunchKernelGGL(attn_kernel, dim3(BB * HH / 16), dim3(256), 0, stream, QKV, Cpr, Xb);
  // output projection -> fp32 d_out with bias (control kernel)
  hipLaunchKernelGGL((gemm256<true>), dim3((M / 256) * (D / 256)), dim3(512), 0, stream,
                     (const __hip_bfloat16*)Xb, (const __hip_bfloat16*)Wob, bo,
                     d_out, M, D, D);
}

// Round 7
// 656.536 us; speedup vs baseline: 1.0800x; 1.0800x over previous
//
#include <hip/hip_runtime.h>
#include <hip/hip_bf16.h>

#define BB 16384
#define KK 3
#define DD 1024
#define HH 16

typedef __attribute__((ext_vector_type(8))) short bf16x8;
typedef __attribute__((ext_vector_type(4))) float f32x4;
typedef unsigned int u32;

__device__ __forceinline__ void load_lds16(const void* g, void* l) {
  __builtin_amdgcn_global_load_lds(
      (const __attribute__((address_space(1))) u32*)g,
      (__attribute__((address_space(3))) u32*)l,
      16, 0, 0);
}

__device__ __forceinline__ unsigned short f2bf(float f) {
  __hip_bfloat16 h = __float2bfloat16(f);
  unsigned short u;
  __builtin_memcpy(&u, &h, 2);
  return u;
}

__device__ __forceinline__ float bf2f(unsigned short u) {
  union { float f; u32 i; } cv;
  cv.i = ((u32)u) << 16;
  return cv.f;
}

// ---------------------------------------------------------------- cast fp32 -> bf16
__global__ void cast_f32_bf16(const float* __restrict__ in,
                              unsigned short* __restrict__ out, int n4) {
  int stride = gridDim.x * blockDim.x;
  for (int i = blockIdx.x * blockDim.x + threadIdx.x; i < n4; i += stride) {
    float4 v = ((const float4*)in)[i];
    ushort4 o;
    o.x = f2bf(v.x);
    o.y = f2bf(v.y);
    o.z = f2bf(v.z);
    o.w = f2bf(v.w);
    ((ushort4*)out)[i] = o;
  }
}

// ---------------------------------------------------------------- GEMM: C = A @ Bt^T + bias
// 256x256 tile, BK=32, 512 threads = 8 waves (2M x 4N), per-wave 128x64 output.
// 4-slot LDS ring (4 x 32KB), stage t+3, vmcnt(8) steady (never 0 mid-loop).
// K-loop = AITER-style "32 MFMA per barrier": ONE s_barrier per tile, NO
// inline lgkmcnt drains. The 12 ds_reads are plain loads; the compiler gates
// each MFMA on exactly the reads it needs with counted lgkmcnt(N) (m97-verified
// behavior), so later reads' latency hides under earlier MFMA clusters and the
// LDS pipe is never force-drained.
// Ring safety: wave's reads of slot (t-1) are register-retired before its
// barrier at tile t (last MFMA of t-1 consumed them); barrier(t) syncs all
// waves; stage(t+3) -> slot (t-1) issues only after that barrier. vmcnt(8) +
// barrier prove slot t's staged data landed block-wide before any read of it.
template <bool OUT_F32>
__global__ __launch_bounds__(512, 2)
void gemm256(const __hip_bfloat16* __restrict__ A,
             const __hip_bfloat16* __restrict__ Bt,
             const float* __restrict__ bias,
             void* __restrict__ Cout,
             int M, int N, int K) {
  __shared__ __align__(128) char lds[131072];

  const int nTn = N >> 8;
  const int nwg = (M >> 8) * nTn;
  int bid = blockIdx.x;
  bid = (bid & 7) * (nwg >> 3) + (bid >> 3);  // bijective XCD swizzle (nwg%8==0)
  const int tm = bid / nTn;
  const int tn = bid % nTn;

  const int tid = threadIdx.x;
  const int l = tid & 63;
  const int w = tid >> 6;
  const int wm = w >> 2;   // 0..1
  const int wn = w & 3;    // 0..3
  const int l15 = l & 15;
  const int g = l >> 4;    // k-chunk group 0..3
  const int l7 = l15 & 7;

  // fragment-read byte offsets inside a 32KB slot (R3-verified, conflicts=0)
  const int aBase = (l15 << 7) + (((wm << 2) + g) ^ l7) * 16;
  const int bBase = 16384 + ((((wn & 1) << 6) + l15) << 7) +
                    ((((wn >> 1) << 2) + g) ^ l7) * 16;

  // staging geometry (dest linear, source pre-swizzled: phys chunk = q ^ (line&7))
  const size_t strideK = (size_t)K * 2;
  const char* Ab = (const char*)A + (size_t)tm * 256 * strideK;
  const char* Bb = (const char*)Bt + (size_t)tn * 256 * strideK;
  const int q = (tid & 7) ^ ((tid >> 3) & 7);
  const size_t g0 = (size_t)((q >> 2) * 128 + (tid >> 3)) * strideK + (q & 3) * 16;
  const size_t g1 = g0 + (size_t)64 * strideK;
  const int sld = tid << 4;

  f32x4 acc[8][4] = {};
  const int nkt = K >> 5;  // BK = 32

#define STAGE_AB(T)                                                       \
  {                                                                       \
    char* sb = lds + (((T) & 3) << 15);                                   \
    const char* ga = Ab + ((size_t)(T) << 6);                             \
    const char* gb = Bb + ((size_t)(T) << 6);                             \
    load_lds16(ga + g0, sb + sld);                                        \
    load_lds16(ga + g1, sb + 8192 + sld);                                 \
    load_lds16(gb + g0, sb + 16384 + sld);                                \
    load_lds16(gb + g1, sb + 24576 + sld);                                \
  }

  STAGE_AB(0);
  STAGE_AB(1);
  STAGE_AB(2);

  for (int kt = 0; kt < nkt; ++kt) {
    // top-of-tile: prove slot kt landed (self: vmcnt; others: barrier)
    if (kt <= nkt - 3)
      asm volatile("s_waitcnt vmcnt(8)" ::: "memory");
    else if (kt == nkt - 2)
      asm volatile("s_waitcnt vmcnt(4)" ::: "memory");
    else
      asm volatile("s_waitcnt vmcnt(0)" ::: "memory");
    __builtin_amdgcn_s_barrier();
    asm volatile("" ::: "memory");  // fence: keep reads below the barrier

    const char* slot = lds + ((kt & 3) << 15);
    bf16x8 bfr[4], af[8];
#pragma unroll
    for (int n = 0; n < 4; ++n)
      bfr[n] = *(const bf16x8*)(slot + bBase + (n << 11));
#pragma unroll
    for (int m = 0; m < 8; ++m)
      af[m] = *(const bf16x8*)(slot + aBase + (m << 11));

    if (kt + 3 < nkt) STAGE_AB(kt + 3);  // overwrites slot (kt-1): safe

    // 32 MFMA, compiler-gated by counted lgkmcnt per operand arrival
    __builtin_amdgcn_s_setprio(1);
#pragma unroll
    for (int m = 0; m < 8; ++m)
#pragma unroll
      for (int n = 0; n < 4; ++n)
        acc[m][n] = __builtin_amdgcn_mfma_f32_16x16x32_bf16(af[m], bfr[n],
                                                            acc[m][n], 0, 0, 0);
    __builtin_amdgcn_s_setprio(0);
  }
#undef STAGE_AB

  // epilogue: C/D layout col = lane&15, row = (lane>>4)*4 + reg  [m89-verified]
  const int cbase = tn * 256 + (wn << 6) + l15;
  float b4[4];
#pragma unroll
  for (int n = 0; n < 4; ++n) b4[n] = bias[cbase + (n << 4)];
  const size_t rbase = (size_t)tm * 256 + (wm << 7) + ((l >> 4) << 2);
#pragma unroll
  for (int m = 0; m < 8; ++m) {
#pragma unroll
    for (int j = 0; j < 4; ++j) {
      const size_t row = rbase + (m << 4) + j;
#pragma unroll
      for (int n = 0; n < 4; ++n) {
        const int col = cbase + (n << 4);
        float v = acc[m][n][j] + b4[n];
        if (OUT_F32)
          ((float*)Cout)[row * N + col] = v;
        else
          ((unsigned short*)Cout)[row * N + col] = f2bf(v);
      }
    }
  }
}

// ---------------------------------------------------------------- attention
// 16 lanes per (b,h); lane x handles dims 4x..4x+3 via ushort4 (8B/lane loads).
__global__ __launch_bounds__(256)
void attn_kernel(const unsigned short* __restrict__ QKV,  // (B*3) x 3072
                 const unsigned short* __restrict__ Cp,   // B x 1024
                 unsigned short* __restrict__ Out) {      // (B*3) x 1024
  const int t = threadIdx.x;
  const int grp = (blockIdx.x << 4) + (t >> 4);
  const int x = t & 15;
  const int b = grp >> 4;   // H = 16
  const int h = grp & 15;

  const size_t col = (size_t)h * 64 + (x << 2);
  const size_t qbase = (size_t)b * 3 * 3072 + col;

  ushort4 cu = *(const ushort4*)&Cp[(size_t)b * 1024 + col];
  float c[4] = {bf2f(cu.x), bf2f(cu.y), bf2f(cu.z), bf2f(cu.w)};

  float q[3][4], kc[3][4], vc[3][4];
#pragma unroll
  for (int i = 0; i < 3; ++i) {
    ushort4 qu = *(const ushort4*)&QKV[qbase + (size_t)i * 3072];
    ushort4 ku = *(const ushort4*)&QKV[qbase + (size_t)i * 3072 + 1024];
    ushort4 vu = *(const ushort4*)&QKV[qbase + (size_t)i * 3072 + 2048];
    q[i][0] = bf2f(qu.x); q[i][1] = bf2f(qu.y); q[i][2] = bf2f(qu.z); q[i][3] = bf2f(qu.w);
    kc[i][0] = bf2f(ku.x) * c[0]; kc[i][1] = bf2f(ku.y) * c[1];
    kc[i][2] = bf2f(ku.z) * c[2]; kc[i][3] = bf2f(ku.w) * c[3];
    vc[i][0] = bf2f(vu.x) * c[0]; vc[i][1] = bf2f(vu.y) * c[1];
    vc[i][2] = bf2f(vu.z) * c[2]; vc[i][3] = bf2f(vu.w) * c[3];
  }

  float s[9];
#pragma unroll
  for (int i = 0; i < 3; ++i)
#pragma unroll
    for (int j = 0; j < 3; ++j)
      s[i * 3 + j] = q[i][0] * kc[j][0] + q[i][1] * kc[j][1] +
                     q[i][2] * kc[j][2] + q[i][3] * kc[j][3];

#pragma unroll
  for (int off = 8; off > 0; off >>= 1)
#pragma unroll
    for (int e = 0; e < 9; ++e)
      s[e] += __shfl_xor(s[e], off, 64);

  const float scale = 0.125f;  // 1/sqrt(64)
#pragma unroll
  for (int i = 0; i < 3; ++i) {
    float s0 = s[i * 3 + 0] * scale;
    float s1 = s[i * 3 + 1] * scale;
    float s2 = s[i * 3 + 2] * scale;
    float m = fmaxf(fmaxf(s0, s1), s2);
    float p0 = expf(s0 - m), p1 = expf(s1 - m), p2 = expf(s2 - m);
    float inv = 1.0f / (p0 + p1 + p2);
    ushort4 o;
    o.x = f2bf((p0 * vc[0][0] + p1 * vc[1][0] + p2 * vc[2][0]) * inv);
    o.y = f2bf((p0 * vc[0][1] + p1 * vc[1][1] + p2 * vc[2][1]) * inv);
    o.z = f2bf((p0 * vc[0][2] + p1 * vc[1][2] + p2 * vc[2][2]) * inv);
    o.w = f2bf((p0 * vc[0][3] + p1 * vc[1][3] + p2 * vc[2][3]) * inv);
    *(ushort4*)&Out[(size_t)(b * 3 + i) * 1024 + col] = o;
  }
}

// ---------------------------------------------------------------- launch
extern "C" void kernel_launch(void* const* d_in, const int* in_sizes, int n_in,
                              void* d_out, int out_size, void* d_ws, size_t ws_size,
                              hipStream_t stream) {
  const float* tokens = (const float*)d_in[0];
  const float* ctx    = (const float*)d_in[1];
  const float* Wq     = (const float*)d_in[2];
  const float* bq     = (const float*)d_in[3];
  const float* Wk     = (const float*)d_in[4];
  const float* bk     = (const float*)d_in[5];
  const float* Wv     = (const float*)d_in[6];
  const float* bv     = (const float*)d_in[7];
  const float* Wc     = (const float*)d_in[8];
  const float* bc     = (const float*)d_in[9];
  const float* Wo     = (const float*)d_in[10];
  const float* bo     = (const float*)d_in[11];

  const int M  = BB * KK;   // 49152 token rows
  const int Mc = BB;        // 16384 ctx rows
  const int D  = DD;        // 1024

  char* p = (char*)d_ws;
  auto carve = [&](size_t bytes) {
    char* r = p;
    p += (bytes + 255) & ~(size_t)255;
    return r;
  };
  unsigned short* Xb   = (unsigned short*)carve((size_t)M * D * 2);  // tokens bf16; reused as attn out
  unsigned short* Cin  = (unsigned short*)carve((size_t)Mc * D * 2);
  unsigned short* Wqkv = (unsigned short*)carve((size_t)3 * D * D * 2);
  unsigned short* Wcb  = (unsigned short*)carve((size_t)D * D * 2);
  unsigned short* Wob  = (unsigned short*)carve((size_t)D * D * 2);
  float*          bqkv = (float*)carve((size_t)3 * D * 4);
  unsigned short* QKV  = (unsigned short*)carve((size_t)M * 3 * D * 2);
  unsigned short* Cpr  = (unsigned short*)carve((size_t)Mc * D * 2);

  hipLaunchKernelGGL(cast_f32_bf16, dim3(4096), dim3(256), 0, stream, tokens, Xb, M * D / 4);
  hipLaunchKernelGGL(cast_f32_bf16, dim3(2048), dim3(256), 0, stream, ctx, Cin, Mc * D / 4);
  hipLaunchKernelGGL(cast_f32_bf16, dim3(512), dim3(256), 0, stream, Wq, Wqkv, D * D / 4);
  hipLaunchKernelGGL(cast_f32_bf16, dim3(512), dim3(256), 0, stream, Wk, Wqkv + D * D, D * D / 4);
  hipLaunchKernelGGL(cast_f32_bf16, dim3(512), dim3(256), 0, stream, Wv, Wqkv + 2 * D * D, D * D / 4);
  hipLaunchKernelGGL(cast_f32_bf16, dim3(512), dim3(256), 0, stream, Wc, Wcb, D * D / 4);
  hipLaunchKernelGGL(cast_f32_bf16, dim3(512), dim3(256), 0, stream, Wo, Wob, D * D / 4);
  hipMemcpyAsync(bqkv, bq, D * 4, hipMemcpyDeviceToDevice, stream);
  hipMemcpyAsync(bqkv + D, bk, D * 4, hipMemcpyDeviceToDevice, stream);
  hipMemcpyAsync(bqkv + 2 * D, bv, D * 4, hipMemcpyDeviceToDevice, stream);

  // QKV projection: (49152 x 1024) @ (1024 x 3072) -> 192*12 = 2304 blocks
  hipLaunchKernelGGL((gemm256<false>), dim3((M / 256) * (3 * D / 256)), dim3(512), 0, stream,
                     (const __hip_bfloat16*)Xb, (const __hip_bfloat16*)Wqkv, bqkv,
                     (void*)QKV, M, 3 * D, D);
  // ctx projection: (16384 x 1024) @ (1024 x 1024) -> 64*4 = 256 blocks
  hipLaunchKernelGGL((gemm256<false>), dim3((Mc / 256) * (D / 256)), dim3(512), 0, stream,
                     (const __hip_bfloat16*)Cin, (const __hip_bfloat16*)Wcb, bc,
                     (void*)Cpr, Mc, D, D);
  // attention (writes into Xb, dead after the QKV GEMM)
  hipLaunchKernelGGL(attn_kernel, dim3(BB * HH / 16), dim3(256), 0, stream, QKV, Cpr, Xb);
  // output projection -> fp32 d_out with bias: 192*4 = 768 blocks
  hipLaunchKernelGGL((gemm256<true>), dim3((M / 256) * (D / 256)), dim3(512), 0, stream,
                     (const __hip_bfloat16*)Xb, (const __hip_bfloat16*)Wob, bo,
                     d_out, M, D, D);
}

// Round 8
// 628.110 us; speedup vs baseline: 1.1289x; 1.0453x over previous
//
#include <hip/hip_runtime.h>
#include <hip/hip_bf16.h>

#define BB 16384
#define KK 3
#define DD 1024
#define HH 16

typedef __attribute__((ext_vector_type(8))) short bf16x8;
typedef __attribute__((ext_vector_type(4))) float f32x4;
typedef unsigned int u32;

__device__ __forceinline__ void load_lds16(const void* g, void* l) {
  __builtin_amdgcn_global_load_lds(
      (const __attribute__((address_space(1))) u32*)g,
      (__attribute__((address_space(3))) u32*)l,
      16, 0, 0);
}

__device__ __forceinline__ unsigned short f2bf(float f) {
  __hip_bfloat16 h = __float2bfloat16(f);
  unsigned short u;
  __builtin_memcpy(&u, &h, 2);
  return u;
}

__device__ __forceinline__ float bf2f(unsigned short u) {
  union { float f; u32 i; } cv;
  cv.i = ((u32)u) << 16;
  return cv.f;
}

// ---------------------------------------------------------------- cast fp32 -> bf16
__global__ void cast_f32_bf16(const float* __restrict__ in,
                              unsigned short* __restrict__ out, int n4) {
  int stride = gridDim.x * blockDim.x;
  for (int i = blockIdx.x * blockDim.x + threadIdx.x; i < n4; i += stride) {
    float4 v = ((const float4*)in)[i];
    ushort4 o;
    o.x = f2bf(v.x);
    o.y = f2bf(v.y);
    o.z = f2bf(v.z);
    o.w = f2bf(v.w);
    ((ushort4*)out)[i] = o;
  }
}

// ---------------------------------------------------------------- GEMM: C = A @ Bt^T + bias
// m201-faithful 8-phase schedule. 256x256 tile, BK=64, 512 thr = 8 waves
// (2M x 4N), wave-tile 128x64. LDS = 2 buffers x (A 32KB + B 32KB) = 128KB.
// Per 2-K-tile iteration, 8 phases; each phase:
//   {ds_read quadrant frags (12/8/4/0) | stage 1 half-tile (2 gload_lds) |
//    [vmcnt(4) at P4/P8] | s_barrier | lgkmcnt(0) | setprio1 16 MFMA setprio0 |
//    s_barrier}
// Full K64-tile held in regs (A 16 + B 8 bf16x8 frags); quadrant MFMA order
// Q(0,0) Q(1,0) Q(0,1) Q(1,1). Stages run 3-5 half-tiles ahead:
//   P1/P2: t1-B, P3/P4: t2-A, P5/P6: t2-B, P7/P8: t3-A.
// vmcnt(4)@P4 forces t1's 4 halves (read P5-8); vmcnt(4)@P8 forces t2's.
// WAR safety: every LDS half overwritten only after the phase whose lgkm0 +
// barrier drained all block-wide reads of its previous occupant.
// Layout per buffer: A [256 rows][128B], B [256 cols][128B] at +32KB;
// phys 16B-chunk = logical ^ (row&7) (pre-swizzled gload source, swizzled
// ds_read; dest linear) -- R3-verified conflict-free.
template <bool OUT_F32>
__global__ __launch_bounds__(512, 2)
void gemm256(const __hip_bfloat16* __restrict__ A,
             const __hip_bfloat16* __restrict__ Bt,
             const float* __restrict__ bias,
             void* __restrict__ Cout,
             int M, int N, int K) {
  __shared__ __align__(128) char lds[131072];

  const int nTn = N >> 8;
  const int nwg = (M >> 8) * nTn;
  int bid = blockIdx.x;
  bid = (bid & 7) * (nwg >> 3) + (bid >> 3);  // bijective XCD swizzle (nwg%8==0)
  const int tm = bid / nTn;
  const int tn = bid % nTn;

  const int tid = threadIdx.x;
  const int l = tid & 63;
  const int w = tid >> 6;
  const int wm = w >> 2;   // 0..1
  const int wn = w & 3;    // 0..3
  const int l15 = l & 15;
  const int g = l >> 4;    // k-chunk group 0..3
  const int l7 = l15 & 7;

  // fragment-read constants (byte offsets within a 64KB buffer)
  const int cs0 = ((g ^ l7) << 4);         // k-half 0 swizzled chunk
  const int cs1 = (((4 | g) ^ l7) << 4);   // k-half 1
  const int aRowB = ((wm << 7) + l15) << 7;            // A row base
  const int bColB = 32768 + (((wn << 6) + l15) << 7);  // B col base

  // staging constants: per thread one 16B slice per instr; dest linear,
  // source chunk pre-swizzled q = (tid&7) ^ ((tid>>3)&7)
  const size_t strideK = (size_t)K * 2;
  const char* Ab = (const char*)A + (size_t)tm * 256 * strideK;
  const char* Bb = (const char*)Bt + (size_t)tn * 256 * strideK;
  const size_t sOff = (size_t)(tid >> 3) * strideK +
                      (size_t)(((tid & 7) ^ ((tid >> 3) & 7)) << 4);
  const int sldst = tid << 4;

  char* const sl0 = lds;            // even tiles
  char* const sl1 = lds + 65536;    // odd tiles

  f32x4 acc[8][4] = {};
  bf16x8 aF[16], bF[8];
  const int njt = K >> 7;  // iterations of 2 K64-tiles

#define STG_A(T, H)                                                        \
  {                                                                        \
    char* d = lds + (((T) & 1) << 16) + ((H) << 14) + sldst;               \
    const char* s = Ab + ((size_t)(T) << 7) +                              \
                    ((size_t)((H) << 7)) * strideK + sOff;                 \
    load_lds16(s, d);                                                      \
    load_lds16(s + 64 * strideK, d + 8192);                                \
  }
#define STG_B(T, H)                                                        \
  {                                                                        \
    char* d = lds + (((T) & 1) << 16) + 32768 + ((H) << 14) + sldst;       \
    const char* s = Bb + ((size_t)(T) << 7) +                              \
                    ((size_t)((H) << 7)) * strideK + sOff;                 \
    load_lds16(s, d);                                                      \
    load_lds16(s + 64 * strideK, d + 8192);                                \
  }
#define RD_A2(SB, m)                                                       \
  aF[2 * (m)] = *(const bf16x8*)((SB) + aRowB + ((m) << 11) + cs0);        \
  aF[2 * (m) + 1] = *(const bf16x8*)((SB) + aRowB + ((m) << 11) + cs1);
#define RD_B2(SB, n)                                                       \
  bF[2 * (n)] = *(const bf16x8*)((SB) + bColB + ((n) << 11) + cs0);        \
  bF[2 * (n) + 1] = *(const bf16x8*)((SB) + bColB + ((n) << 11) + cs1);
#define MFMA_Q(MH, NH)                                                     \
  __builtin_amdgcn_s_setprio(1);                                           \
  _Pragma("unroll") for (int mm = 0; mm < 4; ++mm)                         \
      _Pragma("unroll") for (int nn = 0; nn < 2; ++nn)                     \
          _Pragma("unroll") for (int kh = 0; kh < 2; ++kh)                 \
              acc[(MH)*4 + mm][(NH)*2 + nn] =                              \
                  __builtin_amdgcn_mfma_f32_16x16x32_bf16(                 \
                      aF[2 * ((MH)*4 + mm) + kh],                          \
                      bF[2 * ((NH)*2 + nn) + kh],                          \
                      acc[(MH)*4 + mm][(NH)*2 + nn], 0, 0, 0);             \
  __builtin_amdgcn_s_setprio(0);
#define BAR  __builtin_amdgcn_s_barrier(); asm volatile("" ::: "memory");
#define LGKM0 asm volatile("s_waitcnt lgkmcnt(0)" ::: "memory");

  // prologue: t0 all 4 halves, t1 A halves; vmcnt(4) forces t0's 8 loads
  STG_A(0, 0); STG_A(0, 1); STG_B(0, 0); STG_B(0, 1);
  STG_A(1, 0); STG_A(1, 1);
  asm volatile("s_waitcnt vmcnt(4)" ::: "memory");
  BAR

  for (int j = 0; j < njt; ++j) {
    const int t1 = 2 * j + 1, t2 = 2 * j + 2, t3 = 2 * j + 3;
    const bool full = (j < njt - 1);

    // ---- P1: t0 quadrant (m0-3, n0-1)
    RD_B2(sl0, 0) RD_B2(sl0, 1)
    RD_A2(sl0, 0) RD_A2(sl0, 1) RD_A2(sl0, 2) RD_A2(sl0, 3)
    STG_B(t1, 0)
    BAR LGKM0 MFMA_Q(0, 0) BAR
    // ---- P2: (m4-7, n0-1)
    RD_A2(sl0, 4) RD_A2(sl0, 5) RD_A2(sl0, 6) RD_A2(sl0, 7)
    STG_B(t1, 1)
    BAR LGKM0 MFMA_Q(1, 0) BAR
    // ---- P3: (m0-3, n2-3)
    RD_B2(sl0, 2) RD_B2(sl0, 3)
    if (full) STG_A(t2, 0)
    BAR LGKM0 MFMA_Q(0, 1) BAR
    // ---- P4: (m4-7, n2-3); vmcnt gates t1 readiness for P5
    if (full) STG_A(t2, 1)
    if (full) { asm volatile("s_waitcnt vmcnt(4)" ::: "memory"); }
    else      { asm volatile("s_waitcnt vmcnt(0)" ::: "memory"); }
    BAR MFMA_Q(1, 1) BAR

    // ---- P5: t1 quadrant (m0-3, n0-1)
    RD_B2(sl1, 0) RD_B2(sl1, 1)
    RD_A2(sl1, 0) RD_A2(sl1, 1) RD_A2(sl1, 2) RD_A2(sl1, 3)
    if (full) STG_B(t2, 0)
    BAR LGKM0 MFMA_Q(0, 0) BAR
    // ---- P6: (m4-7, n0-1)
    RD_A2(sl1, 4) RD_A2(sl1, 5) RD_A2(sl1, 6) RD_A2(sl1, 7)
    if (full) STG_B(t2, 1)
    BAR LGKM0 MFMA_Q(1, 0) BAR
    // ---- P7: (m0-3, n2-3)
    RD_B2(sl1, 2) RD_B2(sl1, 3)
    if (full) STG_A(t3, 0)
    BAR LGKM0 MFMA_Q(0, 1) BAR
    // ---- P8: (m4-7, n2-3); vmcnt gates t2 readiness for next P1
    if (full) STG_A(t3, 1)
    if (full) { asm volatile("s_waitcnt vmcnt(4)" ::: "memory"); }
    else      { asm volatile("s_waitcnt vmcnt(0)" ::: "memory"); }
    BAR MFMA_Q(1, 1) BAR
  }
#undef STG_A
#undef STG_B
#undef RD_A2
#undef RD_B2
#undef MFMA_Q
#undef BAR
#undef LGKM0

  // epilogue: C/D layout col = lane&15, row = (lane>>4)*4 + reg  [m89-verified]
  const int cbase = tn * 256 + (wn << 6) + l15;
  float b4[4];
#pragma unroll
  for (int n = 0; n < 4; ++n) b4[n] = bias[cbase + (n << 4)];
  const size_t rbase = (size_t)tm * 256 + (wm << 7) + ((l >> 4) << 2);
#pragma unroll
  for (int m = 0; m < 8; ++m) {
#pragma unroll
    for (int j = 0; j < 4; ++j) {
      const size_t row = rbase + (m << 4) + j;
#pragma unroll
      for (int n = 0; n < 4; ++n) {
        const int col = cbase + (n << 4);
        float v = acc[m][n][j] + b4[n];
        if (OUT_F32)
          ((float*)Cout)[row * N + col] = v;
        else
          ((unsigned short*)Cout)[row * N + col] = f2bf(v);
      }
    }
  }
}

// ---------------------------------------------------------------- attention
// 16 lanes per (b,h); lane x handles dims 4x..4x+3 via ushort4 (8B/lane loads).
__global__ __launch_bounds__(256)
void attn_kernel(const unsigned short* __restrict__ QKV,  // (B*3) x 3072
                 const unsigned short* __restrict__ Cp,   // B x 1024
                 unsigned short* __restrict__ Out) {      // (B*3) x 1024
  const int t = threadIdx.x;
  const int grp = (blockIdx.x << 4) + (t >> 4);
  const int x = t & 15;
  const int b = grp >> 4;   // H = 16
  const int h = grp & 15;

  const size_t col = (size_t)h * 64 + (x << 2);
  const size_t qbase = (size_t)b * 3 * 3072 + col;

  ushort4 cu = *(const ushort4*)&Cp[(size_t)b * 1024 + col];
  float c[4] = {bf2f(cu.x), bf2f(cu.y), bf2f(cu.z), bf2f(cu.w)};

  float q[3][4], kc[3][4], vc[3][4];
#pragma unroll
  for (int i = 0; i < 3; ++i) {
    ushort4 qu = *(const ushort4*)&QKV[qbase + (size_t)i * 3072];
    ushort4 ku = *(const ushort4*)&QKV[qbase + (size_t)i * 3072 + 1024];
    ushort4 vu = *(const ushort4*)&QKV[qbase + (size_t)i * 3072 + 2048];
    q[i][0] = bf2f(qu.x); q[i][1] = bf2f(qu.y); q[i][2] = bf2f(qu.z); q[i][3] = bf2f(qu.w);
    kc[i][0] = bf2f(ku.x) * c[0]; kc[i][1] = bf2f(ku.y) * c[1];
    kc[i][2] = bf2f(ku.z) * c[2]; kc[i][3] = bf2f(ku.w) * c[3];
    vc[i][0] = bf2f(vu.x) * c[0]; vc[i][1] = bf2f(vu.y) * c[1];
    vc[i][2] = bf2f(vu.z) * c[2]; vc[i][3] = bf2f(vu.w) * c[3];
  }

  float s[9];
#pragma unroll
  for (int i = 0; i < 3; ++i)
#pragma unroll
    for (int j = 0; j < 3; ++j)
      s[i * 3 + j] = q[i][0] * kc[j][0] + q[i][1] * kc[j][1] +
                     q[i][2] * kc[j][2] + q[i][3] * kc[j][3];

#pragma unroll
  for (int off = 8; off > 0; off >>= 1)
#pragma unroll
    for (int e = 0; e < 9; ++e)
      s[e] += __shfl_xor(s[e], off, 64);

  const float scale = 0.125f;  // 1/sqrt(64)
#pragma unroll
  for (int i = 0; i < 3; ++i) {
    float s0 = s[i * 3 + 0] * scale;
    float s1 = s[i * 3 + 1] * scale;
    float s2 = s[i * 3 + 2] * scale;
    float m = fmaxf(fmaxf(s0, s1), s2);
    float p0 = expf(s0 - m), p1 = expf(s1 - m), p2 = expf(s2 - m);
    float inv = 1.0f / (p0 + p1 + p2);
    ushort4 o;
    o.x = f2bf((p0 * vc[0][0] + p1 * vc[1][0] + p2 * vc[2][0]) * inv);
    o.y = f2bf((p0 * vc[0][1] + p1 * vc[1][1] + p2 * vc[2][1]) * inv);
    o.z = f2bf((p0 * vc[0][2] + p1 * vc[1][2] + p2 * vc[2][2]) * inv);
    o.w = f2bf((p0 * vc[0][3] + p1 * vc[1][3] + p2 * vc[2][3]) * inv);
    *(ushort4*)&Out[(size_t)(b * 3 + i) * 1024 + col] = o;
  }
}

// ---------------------------------------------------------------- launch
extern "C" void kernel_launch(void* const* d_in, const int* in_sizes, int n_in,
                              void* d_out, int out_size, void* d_ws, size_t ws_size,
                              hipStream_t stream) {
  const float* tokens = (const float*)d_in[0];
  const float* ctx    = (const float*)d_in[1];
  const float* Wq     = (const float*)d_in[2];
  const float* bq     = (const float*)d_in[3];
  const float* Wk     = (const float*)d_in[4];
  const float* bk     = (const float*)d_in[5];
  const float* Wv     = (const float*)d_in[6];
  const float* bv     = (const float*)d_in[7];
  const float* Wc     = (const float*)d_in[8];
  const float* bc     = (const float*)d_in[9];
  const float* Wo     = (const float*)d_in[10];
  const float* bo     = (const float*)d_in[11];

  const int M  = BB * KK;   // 49152 token rows
  const int Mc = BB;        // 16384 ctx rows
  const int D  = DD;        // 1024

  char* p = (char*)d_ws;
  auto carve = [&](size_t bytes) {
    char* r = p;
    p += (bytes + 255) & ~(size_t)255;
    return r;
  };
  unsigned short* Xb   = (unsigned short*)carve((size_t)M * D * 2);  // tokens bf16; reused as attn out
  unsigned short* Cin  = (unsigned short*)carve((size_t)Mc * D * 2);
  unsigned short* Wqkv = (unsigned short*)carve((size_t)3 * D * D * 2);
  unsigned short* Wcb  = (unsigned short*)carve((size_t)D * D * 2);
  unsigned short* Wob  = (unsigned short*)carve((size_t)D * D * 2);
  float*          bqkv = (float*)carve((size_t)3 * D * 4);
  unsigned short* QKV  = (unsigned short*)carve((size_t)M * 3 * D * 2);
  unsigned short* Cpr  = (unsigned short*)carve((size_t)Mc * D * 2);

  hipLaunchKernelGGL(cast_f32_bf16, dim3(4096), dim3(256), 0, stream, tokens, Xb, M * D / 4);
  hipLaunchKernelGGL(cast_f32_bf16, dim3(2048), dim3(256), 0, stream, ctx, Cin, Mc * D / 4);
  hipLaunchKernelGGL(cast_f32_bf16, dim3(512), dim3(256), 0, stream, Wq, Wqkv, D * D / 4);
  hipLaunchKernelGGL(cast_f32_bf16, dim3(512), dim3(256), 0, stream, Wk, Wqkv + D * D, D * D / 4);
  hipLaunchKernelGGL(cast_f32_bf16, dim3(512), dim3(256), 0, stream, Wv, Wqkv + 2 * D * D, D * D / 4);
  hipLaunchKernelGGL(cast_f32_bf16, dim3(512), dim3(256), 0, stream, Wc, Wcb, D * D / 4);
  hipLaunchKernelGGL(cast_f32_bf16, dim3(512), dim3(256), 0, stream, Wo, Wob, D * D / 4);
  hipMemcpyAsync(bqkv, bq, D * 4, hipMemcpyDeviceToDevice, stream);
  hipMemcpyAsync(bqkv + D, bk, D * 4, hipMemcpyDeviceToDevice, stream);
  hipMemcpyAsync(bqkv + 2 * D, bv, D * 4, hipMemcpyDeviceToDevice, stream);

  // QKV projection: (49152 x 1024) @ (1024 x 3072) -> 192*12 = 2304 blocks
  hipLaunchKernelGGL((gemm256<false>), dim3((M / 256) * (3 * D / 256)), dim3(512), 0, stream,
                     (const __hip_bfloat16*)Xb, (const __hip_bfloat16*)Wqkv, bqkv,
                     (void*)QKV, M, 3 * D, D);
  // ctx projection: (16384 x 1024) @ (1024 x 1024) -> 64*4 = 256 blocks
  hipLaunchKernelGGL((gemm256<false>), dim3((Mc / 256) * (D / 256)), dim3(512), 0, stream,
                     (const __hip_bfloat16*)Cin, (const __hip_bfloat16*)Wcb, bc,
                     (void*)Cpr, Mc, D, D);
  // attention (writes into Xb, dead after the QKV GEMM)
  hipLaunchKernelGGL(attn_kernel, dim3(BB * HH / 16), dim3(256), 0, stream, QKV, Cpr, Xb);
  // output projection -> fp32 d_out with bias: 192*4 = 768 blocks
  hipLaunchKernelGGL((gemm256<true>), dim3((M / 256) * (D / 256)), dim3(512), 0, stream,
                     (const __hip_bfloat16*)Xb, (const __hip_bfloat16*)Wob, bo,
                     d_out, M, D, D);
}